// Round 22
// baseline (177.273 us; speedup 1.0000x reference)
//
#include <hip/hip_runtime.h>
#include <hip/hip_bf16.h>

#define EMBED 1024
#define NHEAD 16
#define HDIM  64
#define BATCH 4
#define SEQ   2048
#define BT    (BATCH*SEQ)
#define NQKV  (3*EMBED)

using bf16x8 = __attribute__((ext_vector_type(8))) short;
using f32x4  = __attribute__((ext_vector_type(4))) float;

__device__ __forceinline__ unsigned short f2bf(float f){
  union { float f; unsigned u; } v; v.f = f;
  unsigned r = v.u + 0x7FFFu + ((v.u >> 16) & 1u);
  return (unsigned short)(r >> 16);
}

// raw 2^x (gfx950 v_exp_f32). Denormal results flush to 0 -- fine for softmax.
__device__ __forceinline__ float exp2_hw(float x){
  float r; asm("v_exp_f32 %0, %1" : "=v"(r) : "v"(x)); return r;
}
// packed f32x2 -> bf16x2 in one instruction (T12 recipe; no builtin exists)
__device__ __forceinline__ unsigned cvtpk_bf16(float lo, float hi){
  unsigned r; asm("v_cvt_pk_bf16_f32 %0, %1, %2" : "=v"(r) : "v"(lo), "v"(hi));
  return r;
}

__device__ __forceinline__ void gload_lds16(const void* g, void* l){
  __builtin_amdgcn_global_load_lds(
      (const __attribute__((address_space(1))) void*)g,
      (__attribute__((address_space(3))) void*)l, 16, 0, 0);
}

// ---------------- fp32 -> bf16 elementwise convert ----------------
__global__ __launch_bounds__(256) void cvt_f32_bf16_k(
    const float* __restrict__ in, unsigned short* __restrict__ out, int n)
{
  int i = (blockIdx.x * 256 + threadIdx.x) * 4;
  if (i >= n) return;
  float4 v = *(const float4*)&in[i];
  ushort4 o;
  o.x = f2bf(v.x); o.y = f2bf(v.y); o.z = f2bf(v.z); o.w = f2bf(v.w);
  *(ushort4*)&out[i] = o;
}

// ------------- fp32 [R][C] -> bf16 transposed [C][R] -------------
__global__ __launch_bounds__(256) void transpose_cvt_k(
    const float* __restrict__ in, unsigned short* __restrict__ out, int R, int C)
{
  __shared__ float tile[32][33];
  int tx = threadIdx.x, ty = threadIdx.y;
  int c0 = blockIdx.x * 32, r0 = blockIdx.y * 32;
#pragma unroll
  for (int j = ty; j < 32; j += 8)
    tile[j][tx] = in[(size_t)(r0 + j) * C + c0 + tx];
  __syncthreads();
#pragma unroll
  for (int j = ty; j < 32; j += 8)
    out[(size_t)(c0 + j) * R + r0 + tx] = f2bf(tile[tx][j]);
}

// ------ bf16 QKV GEMM: 128x256 tile, BK=32, 8 waves, 48 KB LDS -------------
// R21 post-mortem: gemm0 is staging-rate-bound (~17 B/cyc/CU, 806 MB total).
// BN=256 cuts staged bytes to 604 MB at the SAME concurrency tier: 48 KB LDS
// -> 2 blocks/CU, VGPR ~72 -> 4 waves/SIMD = 16 waves/CU. 8 waves (2M x 4N),
// per-wave 64x64 = the proven inner loop unchanged. Counted vmcnt(3).
__global__ __launch_bounds__(512) void gemm_qkv(
    const unsigned short* __restrict__ A,
    const unsigned short* __restrict__ Bt,
    const float* __restrict__ bias,
    unsigned short* __restrict__ qp,
    unsigned short* __restrict__ kp,
    unsigned short* __restrict__ vp,
    int M, int N, int K)
{
  __shared__ unsigned short As[2][128 * 32];
  __shared__ unsigned short Bs[2][256 * 32];
  const int tid = threadIdx.x;          // 0..511
  const int w = tid >> 6, lane = tid & 63;
  const int lr = lane & 15, lg = lane >> 4;
  const int wm = (w >> 2) * 64, wn = (w & 3) * 64;
  // bijective XCD swizzle (nwg = 768, %8==0), M-slab per XCD, N fastest
  const int gy = gridDim.y;             // 12
  const int lin = (int)(blockIdx.y * gridDim.x + blockIdx.x);
  const int cpx = (int)(gridDim.x * gy) >> 3;
  const int wg = (lin & 7) * cpx + (lin >> 3);
  const int m0 = (wg / gy) * 128, n0 = (wg % gy) * 256;
  f32x4 acc[4][4] = {};

  // staging: 1 A-chunk + 2 B-chunks of 16B per thread per K-tile
  int fa = tid * 8;
  const int goffA = (fa >> 5) * K + (fa & 31);
  int goffB[2], dstB[2];
#pragma unroll
  for (int i = 0; i < 2; i++) {
    int f = (tid + i * 512) * 8;
    goffB[i] = (f >> 5) * K + (f & 31);
    dstB[i] = f;
  }
  const unsigned short* pA = A + (size_t)m0 * K;
  const unsigned short* pB = Bt + (size_t)n0 * K;

  const int nkt = K >> 5;   // 32

  // prologue: stage tile 0 into buf 0
  gload_lds16(pA + goffA, &As[0][fa]);
#pragma unroll
  for (int i = 0; i < 2; i++)
    gload_lds16(pB + goffB[i], &Bs[0][dstB[i]]);

  int cur = 0;
  for (int t = 0; t < nkt; t++) {
    if (t + 1 < nkt) {
      const int kt = (t + 1) << 5;
      gload_lds16(pA + goffA + kt, &As[cur ^ 1][fa]);
#pragma unroll
      for (int i = 0; i < 2; i++)
        gload_lds16(pB + goffB[i] + kt, &Bs[cur ^ 1][dstB[i]]);
      asm volatile("s_waitcnt vmcnt(3)" ::: "memory");  // own tile-t landed
    } else {
      asm volatile("s_waitcnt vmcnt(0)" ::: "memory");
    }
    __builtin_amdgcn_s_barrier();          // tile t visible to all waves
    __builtin_amdgcn_sched_barrier(0);

    bf16x8 af[4], bv[4];
#pragma unroll
    for (int mi = 0; mi < 4; mi++)
      af[mi] = *(const bf16x8*)&As[cur][(wm + mi * 16 + lr) * 32 + lg * 8];
#pragma unroll
    for (int ni = 0; ni < 4; ni++)
      bv[ni] = *(const bf16x8*)&Bs[cur][(wn + ni * 16 + lr) * 32 + lg * 8];
    __builtin_amdgcn_s_setprio(1);
#pragma unroll
    for (int mi = 0; mi < 4; mi++)
#pragma unroll
      for (int ni = 0; ni < 4; ni++)
        acc[mi][ni] = __builtin_amdgcn_mfma_f32_16x16x32_bf16(af[mi], bv[ni], acc[mi][ni], 0, 0, 0);
    __builtin_amdgcn_s_setprio(0);

    asm volatile("s_waitcnt lgkmcnt(0)" ::: "memory");  // LDS reads retired
    __builtin_amdgcn_s_barrier();          // readers done with buf[cur]
    cur ^= 1;
  }

  // ---- epilogue: scatter to Q/K (row-major, Q pre-scaled) and V^T ----
#pragma unroll
  for (int mi = 0; mi < 4; mi++)
#pragma unroll
    for (int ni = 0; ni < 4; ni++) {
      const int rowb = m0 + wm + mi * 16 + lg * 4;
      const int colb = n0 + wn + ni * 16 + lr;
      const float bv_ = bias[colb];
      int s = colb >> 10, hh = (colb & 1023) >> 6, d = colb & 63;
      int b = rowb >> 11, t = rowb & 2047;
      if (s == 2) {
        ushort4 o4;
        o4.x = f2bf(acc[mi][ni][0] + bv_);
        o4.y = f2bf(acc[mi][ni][1] + bv_);
        o4.z = f2bf(acc[mi][ni][2] + bv_);
        o4.w = f2bf(acc[mi][ni][3] + bv_);
        *(ushort4*)&vp[((size_t)(b * NHEAD + hh) * HDIM + d) * SEQ + t] = o4;
      } else {
        unsigned short* dst_ = (s == 0) ? qp : kp;
        const float scl = (s == 0) ? 0.18033688f : 1.0f;   // 1/sqrt(D)*log2e
#pragma unroll
        for (int r = 0; r < 4; r++)
          dst_[((size_t)(b * NHEAD + hh) * SEQ + t + r) * HDIM + d] =
              f2bf((acc[mi][ni][r] + bv_) * scl);
      }
    }
}

// -------- bf16 GEMM, B^T layout; 128x128 tile, BK=32, 32 KB LDS ------------
// R17-proven (output projection): counted-vmcnt loop, ~5 blocks/CU.
__global__ __launch_bounds__(256) void gemm_out(
    const unsigned short* __restrict__ A,
    const unsigned short* __restrict__ Bt,
    const float* __restrict__ bias,
    float* __restrict__ outp,
    int M, int N, int K)
{
  __shared__ unsigned short As[2][128 * 32];
  __shared__ unsigned short Bs[2][128 * 32];
  const int tid = threadIdx.x;
  const int w = tid >> 6, lane = tid & 63;
  const int lr = lane & 15, lg = lane >> 4;
  const int gy = gridDim.y;
  const int lin = (int)(blockIdx.y * gridDim.x + blockIdx.x);
  const int cpx = (int)(gridDim.x * gy) >> 3;
  const int wg = (lin & 7) * cpx + (lin >> 3);
  const int m0 = (wg / gy) * 128, n0 = (wg % gy) * 128;
  const int wm = (w >> 1) * 64, wn = (w & 1) * 64;
  f32x4 acc[4][4] = {};

  int goff[2], dst[2];
#pragma unroll
  for (int i = 0; i < 2; i++) {
    int f = (w * 2 + i) * 512 + lane * 8;
    goff[i] = (f >> 5) * K + (f & 31);
    dst[i] = f;
  }
  const unsigned short* pA = A + (size_t)m0 * K;
  const unsigned short* pB = Bt + (size_t)n0 * K;

  const int nkt = K >> 5;

#pragma unroll
  for (int i = 0; i < 2; i++) {
    gload_lds16(pA + goff[i], &As[0][dst[i]]);
    gload_lds16(pB + goff[i], &Bs[0][dst[i]]);
  }

  int cur = 0;
  for (int t = 0; t < nkt; t++) {
    if (t + 1 < nkt) {
      const int kt = (t + 1) << 5;
#pragma unroll
      for (int i = 0; i < 2; i++) {
        gload_lds16(pA + goff[i] + kt, &As[cur ^ 1][dst[i]]);
        gload_lds16(pB + goff[i] + kt, &Bs[cur ^ 1][dst[i]]);
      }
      asm volatile("s_waitcnt vmcnt(4)" ::: "memory");
    } else {
      asm volatile("s_waitcnt vmcnt(0)" ::: "memory");
    }
    __builtin_amdgcn_s_barrier();
    __builtin_amdgcn_sched_barrier(0);

    bf16x8 af[4], bv[4];
#pragma unroll
    for (int mi = 0; mi < 4; mi++)
      af[mi] = *(const bf16x8*)&As[cur][(wm + mi * 16 + lr) * 32 + lg * 8];
#pragma unroll
    for (int ni = 0; ni < 4; ni++)
      bv[ni] = *(const bf16x8*)&Bs[cur][(wn + ni * 16 + lr) * 32 + lg * 8];
    __builtin_amdgcn_s_setprio(1);
#pragma unroll
    for (int mi = 0; mi < 4; mi++)
#pragma unroll
      for (int ni = 0; ni < 4; ni++)
        acc[mi][ni] = __builtin_amdgcn_mfma_f32_16x16x32_bf16(af[mi], bv[ni], acc[mi][ni], 0, 0, 0);
    __builtin_amdgcn_s_setprio(0);

    asm volatile("s_waitcnt lgkmcnt(0)" ::: "memory");
    __builtin_amdgcn_s_barrier();
    cur ^= 1;
  }

#pragma unroll
  for (int mi = 0; mi < 4; mi++)
#pragma unroll
    for (int ni = 0; ni < 4; ni++) {
      const int rowb = m0 + wm + mi * 16 + lg * 4;
      const int colb = n0 + wn + ni * 16 + lr;
      const float bv_ = bias[colb];
#pragma unroll
      for (int r = 0; r < 4; r++)
        outp[(size_t)(rowb + r) * N + colb] = acc[mi][ni][r] + bv_;
    }
}

// --------- softmax for one 16q x 64k fragment (swapped S^T layout) ---------
__device__ __forceinline__ void softmax_frag(
    f32x4 (&s)[4], float& m, f32x4& su, f32x4 (&o)[4],
    unsigned short* psrow, int qrow, int kbase, bool needmask,
    int lg, int lr, int pswz)
{
  const float NEG = -1e30f;
  if (needmask) {
#pragma unroll
    for (int n = 0; n < 4; n++)
#pragma unroll
      for (int r = 0; r < 4; r++) {
        if (kbase + n * 16 + lg * 4 + r > qrow) s[n][r] = NEG;
      }
  }
  // tree max (v_max3-friendly)
  float t0 = fmaxf(fmaxf(s[0][0], s[0][1]), fmaxf(s[0][2], s[0][3]));
  float t1 = fmaxf(fmaxf(s[1][0], s[1][1]), fmaxf(s[1][2], s[1][3]));
  float t2 = fmaxf(fmaxf(s[2][0], s[2][1]), fmaxf(s[2][2], s[2][3]));
  float t3 = fmaxf(fmaxf(s[3][0], s[3][1]), fmaxf(s[3][2], s[3][3]));
  float pm = fmaxf(fmaxf(t0, t1), fmaxf(t2, t3));
  // defer-max (T13): common path skips the cross-lane reduce entirely
  if (__any(pm > m + 8.f)) {
    pm = fmaxf(pm, __shfl_xor(pm, 16, 64));
    pm = fmaxf(pm, __shfl_xor(pm, 32, 64));
    float mn = fmaxf(m, pm);
    float fac = exp2_hw(m - mn);
    m = mn;
    float fr[4];
#pragma unroll
    for (int r = 0; r < 4; r++) fr[r] = __shfl(fac, lg * 4 + r, 64);
#pragma unroll
    for (int r = 0; r < 4; r++) su[r] *= fr[r];
#pragma unroll
    for (int n = 0; n < 4; n++)
#pragma unroll
      for (int r = 0; r < 4; r++) o[n][r] *= fr[r];
  }
#pragma unroll
  for (int n = 0; n < 4; n++) {
    float p0 = exp2_hw(s[n][0] - m);
    float p1 = exp2_hw(s[n][1] - m);
    float p2 = exp2_hw(s[n][2] - m);
    float p3 = exp2_hw(s[n][3] - m);
    uint2 pk;
    pk.x = cvtpk_bf16(p0, p1);
    pk.y = cvtpk_bf16(p2, p3);
    int E = (lr * 64 + n * 16 + lg * 4) ^ pswz;
    *(uint2*)&psrow[E] = pk;
  }
}

// ------- causal flash attention, QBLK=128, 8 waves x 1 q-frag each ---------
// R21-proven best: grid (8,64), 512 threads, 16 waves/CU. Unchanged.
__global__ __launch_bounds__(512) void attn_k(
    const unsigned short* __restrict__ Q,
    const unsigned short* __restrict__ K,
    const unsigned short* __restrict__ Vt,
    unsigned short* __restrict__ Y)
{
  __shared__ unsigned short Ks[2][64 * 64];
  __shared__ unsigned short Vs[2][64 * 64];
  __shared__ unsigned short Ps[8][16 * 64];

  const int tid = threadIdx.x;          // 0..511
  const int w = tid >> 6, lane = tid & 63;
  const int lr = lane & 15, lg = lane >> 4;
  const int bh = blockIdx.y;
  const int b = bh >> 4, h = bh & 15;
  const size_t base = (size_t)bh * SEQ * HDIM;
  const float NEG = -1e30f;
  const int pswz = (lr & 7) << 3;

  bf16x8 ones;
#pragma unroll
  for (int e = 0; e < 8; e++) ones[e] = (short)0x3F80;  // bf16 1.0

  // staging geometry (linear LDS dest, pre-swizzled global source)
  const int r0_ = tid >> 3, c0_ = ((tid & 7) ^ (r0_ & 7)) * 8;

  for (int seg = 0; seg < 2; seg++) {
    const int qb = seg ? (int)blockIdx.x : (15 - (int)blockIdx.x);
    const int qw0 = qb * 128 + w * 16;   // this wave's 16 q-rows
    const int nk = 2 * qb + 2;

    bf16x8 aq[2];
#pragma unroll
    for (int kk = 0; kk < 2; kk++)
      aq[kk] = *(const bf16x8*)
          &Q[base + (size_t)(qw0 + lr) * HDIM + kk * 32 + lg * 8];

    f32x4 o[4] = {};
    f32x4 su = {};
    float m = NEG;

    // stage tile 0 into buf 0
    gload_lds16(K  + base + (size_t)r0_ * HDIM + c0_, &Ks[0][tid * 8]);
    gload_lds16(Vt + base + (size_t)r0_ * SEQ  + c0_, &Vs[0][tid * 8]);
    __syncthreads();

    int cur = 0;
    for (int kb = 0; kb < nk; kb++) {
      if (kb + 1 < nk) {
        gload_lds16(K  + base + (size_t)((kb + 1) * 64 + r0_) * HDIM + c0_,
                    &Ks[cur ^ 1][tid * 8]);
        gload_lds16(Vt + base + (size_t)r0_ * SEQ + (kb + 1) * 64 + c0_,
                    &Vs[cur ^ 1][tid * 8]);
      }

      // fully-masked (wave,tile) pairs skip compute (barrier still hit)
      const bool active = (kb * 64 <= qw0 + 15);
      if (active) {
        // ---- S^T = K Q^T ----
        f32x4 s[4] = {};
        __builtin_amdgcn_s_setprio(1);
#pragma unroll
        for (int kk = 0; kk < 2; kk++) {
          bf16x8 bk[4];
#pragma unroll
          for (int n = 0; n < 4; n++) {
            int E = (n * 16 + lr) * 64 + kk * 32 + lg * 8;
            bk[n] = *(const bf16x8*)&Ks[cur][E ^ pswz];
          }
#pragma unroll
          for (int n = 0; n < 4; n++)
            s[n] = __builtin_amdgcn_mfma_f32_16x16x32_bf16(bk[n], aq[kk], s[n], 0, 0, 0);
        }
        __builtin_amdgcn_s_setprio(0);

        const int kbase = kb * 64;
        softmax_frag(s, m, su, o, &Ps[w][0],
                     qw0 + lr, kbase, kbase + 63 > qw0, lg, lr, pswz);

        // ---- O += P V ; row-sum via ones-column MFMA ----
        __builtin_amdgcn_s_setprio(1);
#pragma unroll
        for (int kc = 0; kc < 2; kc++) {
          bf16x8 ap = *(const bf16x8*)&Ps[w][(lr * 64 + kc * 32 + lg * 8) ^ pswz];
          su = __builtin_amdgcn_mfma_f32_16x16x32_bf16(ap, ones, su, 0, 0, 0);
#pragma unroll
          for (int n = 0; n < 4; n++) {
            int E = (n * 16 + lr) * 64 + kc * 32 + lg * 8;
            bf16x8 bv = *(const bf16x8*)&Vs[cur][E ^ pswz];
            o[n] = __builtin_amdgcn_mfma_f32_16x16x32_bf16(ap, bv, o[n], 0, 0, 0);
          }
        }
        __builtin_amdgcn_s_setprio(0);
      }

      __syncthreads();
      cur ^= 1;
    }

    // ---- per-seg epilogue: normalize (su already in O-layout), write Y ----
    float inv[4];
#pragma unroll
    for (int r = 0; r < 4; r++) inv[r] = 1.f / su[r];
#pragma unroll
    for (int n = 0; n < 4; n++)
#pragma unroll
      for (int r = 0; r < 4; r++) {
        int col = h * HDIM + n * 16 + lr;
        int t0 = qw0 + lg * 4 + r;
        Y[((size_t)(b * SEQ + t0)) * EMBED + col] = f2bf(o[n][r] * inv[r]);
      }
  }
}

// ---------------- host launch ----------------
extern "C" void kernel_launch(void* const* d_in, const int* in_sizes, int n_in,
                              void* d_out, int out_size, void* d_ws, size_t ws_size,
                              hipStream_t stream) {
  const float* x     = (const float*)d_in[0];
  const float* w_qkv = (const float*)d_in[1];
  const float* b_qkv = (const float*)d_in[2];
  const float* w_out = (const float*)d_in[3];
  const float* b_out = (const float*)d_in[4];
  float* outp = (float*)d_out;

  char* ws = (char*)d_ws;
  unsigned short* xb    = (unsigned short*)ws; ws += (size_t)BT * EMBED * 2;
  unsigned short* wqkvT = (unsigned short*)ws; ws += (size_t)NQKV * EMBED * 2;
  unsigned short* woutT = (unsigned short*)ws; ws += (size_t)EMBED * EMBED * 2;
  unsigned short* Qb    = (unsigned short*)ws; ws += (size_t)BATCH * NHEAD * SEQ * HDIM * 2;
  unsigned short* Kb    = (unsigned short*)ws; ws += (size_t)BATCH * NHEAD * SEQ * HDIM * 2;
  unsigned short* Vb    = (unsigned short*)ws; ws += (size_t)BATCH * NHEAD * SEQ * HDIM * 2;
  unsigned short* Yb    = (unsigned short*)ws; ws += (size_t)BT * EMBED * 2;

  cvt_f32_bf16_k<<<(BT * EMBED) / 1024, 256, 0, stream>>>(x, xb, BT * EMBED);
  transpose_cvt_k<<<dim3(NQKV / 32, EMBED / 32), dim3(32, 8), 0, stream>>>(w_qkv, wqkvT, EMBED, NQKV);
  transpose_cvt_k<<<dim3(EMBED / 32, EMBED / 32), dim3(32, 8), 0, stream>>>(w_out, woutT, EMBED, EMBED);

  // QKV projection: 128x256 tiles, 8 waves, 768 blocks
  gemm_qkv<<<dim3(BT / 128, NQKV / 256), 512, 0, stream>>>(
      xb, wqkvT, b_qkv, Qb, Kb, Vb, BT, NQKV, EMBED);

  attn_k<<<dim3(8, BATCH * NHEAD), 512, 0, stream>>>(Qb, Kb, Vb, Yb);

  // output projection: 128x128 tiles (R17-proven)
  gemm_out<<<dim3(BT / 128, EMBED / 128), 256, 0, stream>>>(
      Yb, woutT, b_out, outp, BT, EMBED, EMBED);
}

// Round 23
// 174.711 us; speedup vs baseline: 1.0147x; 1.0147x over previous
//
#include <hip/hip_runtime.h>
#include <hip/hip_bf16.h>

#define EMBED 1024
#define NHEAD 16
#define HDIM  64
#define BATCH 4
#define SEQ   2048
#define BT    (BATCH*SEQ)
#define NQKV  (3*EMBED)

using bf16x8 = __attribute__((ext_vector_type(8))) short;
using f32x4  = __attribute__((ext_vector_type(4))) float;

__device__ __forceinline__ unsigned short f2bf(float f){
  union { float f; unsigned u; } v; v.f = f;
  unsigned r = v.u + 0x7FFFu + ((v.u >> 16) & 1u);
  return (unsigned short)(r >> 16);
}

// raw 2^x (gfx950 v_exp_f32). Denormal results flush to 0 -- fine for softmax.
__device__ __forceinline__ float exp2_hw(float x){
  float r; asm("v_exp_f32 %0, %1" : "=v"(r) : "v"(x)); return r;
}
// packed f32x2 -> bf16x2 in one instruction (T12 recipe; no builtin exists)
__device__ __forceinline__ unsigned cvtpk_bf16(float lo, float hi){
  unsigned r; asm("v_cvt_pk_bf16_f32 %0, %1, %2" : "=v"(r) : "v"(lo), "v"(hi));
  return r;
}

__device__ __forceinline__ void gload_lds16(const void* g, void* l){
  __builtin_amdgcn_global_load_lds(
      (const __attribute__((address_space(1))) void*)g,
      (__attribute__((address_space(3))) void*)l, 16, 0, 0);
}

// ---------------- fp32 -> bf16 elementwise convert ----------------
__global__ __launch_bounds__(256) void cvt_f32_bf16_k(
    const float* __restrict__ in, unsigned short* __restrict__ out, int n)
{
  int i = (blockIdx.x * 256 + threadIdx.x) * 4;
  if (i >= n) return;
  float4 v = *(const float4*)&in[i];
  ushort4 o;
  o.x = f2bf(v.x); o.y = f2bf(v.y); o.z = f2bf(v.z); o.w = f2bf(v.w);
  *(ushort4*)&out[i] = o;
}

// ------------- fp32 [R][C] -> bf16 transposed [C][R] -------------
__global__ __launch_bounds__(256) void transpose_cvt_k(
    const float* __restrict__ in, unsigned short* __restrict__ out, int R, int C)
{
  __shared__ float tile[32][33];
  int tx = threadIdx.x, ty = threadIdx.y;
  int c0 = blockIdx.x * 32, r0 = blockIdx.y * 32;
#pragma unroll
  for (int j = ty; j < 32; j += 8)
    tile[j][tx] = in[(size_t)(r0 + j) * C + c0 + tx];
  __syncthreads();
#pragma unroll
  for (int j = ty; j < 32; j += 8)
    out[(size_t)(c0 + j) * R + r0 + tx] = f2bf(tile[tx][j]);
}

// -------- bf16 GEMM, B^T layout; 128x128 tile, BK=32, 32 KB LDS ------------
// R17-proven best: concurrency (blocks/CU) sets the per-step wall; BK=32
// dbuf = 32 KB -> ~5 blocks/CU; counted-vmcnt loop per R14.
template<int EPI>
__global__ __launch_bounds__(256) void gemm_bt(
    const unsigned short* __restrict__ A,
    const unsigned short* __restrict__ Bt,
    const float* __restrict__ bias,
    unsigned short* __restrict__ qp,
    unsigned short* __restrict__ kp,
    unsigned short* __restrict__ vp,
    float* __restrict__ outp,
    int M, int N, int K)
{
  __shared__ unsigned short As[2][128 * 32];
  __shared__ unsigned short Bs[2][128 * 32];
  const int tid = threadIdx.x;
  const int w = tid >> 6, lane = tid & 63;
  const int lr = lane & 15, lg = lane >> 4;
  const int gy = gridDim.y;
  const int lin = (int)(blockIdx.y * gridDim.x + blockIdx.x);
  const int cpx = (int)(gridDim.x * gy) >> 3;
  const int wg = (lin & 7) * cpx + (lin >> 3);
  const int m0 = (wg / gy) * 128, n0 = (wg % gy) * 128;
  const int wm = (w >> 1) * 64, wn = (w & 1) * 64;
  f32x4 acc[4][4] = {};

  int goff[2], dst[2];
#pragma unroll
  for (int i = 0; i < 2; i++) {
    int f = (w * 2 + i) * 512 + lane * 8;
    goff[i] = (f >> 5) * K + (f & 31);
    dst[i] = f;
  }
  const unsigned short* pA = A + (size_t)m0 * K;
  const unsigned short* pB = Bt + (size_t)n0 * K;

  const int nkt = K >> 5;

#pragma unroll
  for (int i = 0; i < 2; i++) {
    gload_lds16(pA + goff[i], &As[0][dst[i]]);
    gload_lds16(pB + goff[i], &Bs[0][dst[i]]);
  }

  int cur = 0;
  for (int t = 0; t < nkt; t++) {
    if (t + 1 < nkt) {
      const int kt = (t + 1) << 5;
#pragma unroll
      for (int i = 0; i < 2; i++) {
        gload_lds16(pA + goff[i] + kt, &As[cur ^ 1][dst[i]]);
        gload_lds16(pB + goff[i] + kt, &Bs[cur ^ 1][dst[i]]);
      }
      asm volatile("s_waitcnt vmcnt(4)" ::: "memory");
    } else {
      asm volatile("s_waitcnt vmcnt(0)" ::: "memory");
    }
    __builtin_amdgcn_s_barrier();
    __builtin_amdgcn_sched_barrier(0);

    bf16x8 af[4], bv[4];
#pragma unroll
    for (int mi = 0; mi < 4; mi++)
      af[mi] = *(const bf16x8*)&As[cur][(wm + mi * 16 + lr) * 32 + lg * 8];
#pragma unroll
    for (int ni = 0; ni < 4; ni++)
      bv[ni] = *(const bf16x8*)&Bs[cur][(wn + ni * 16 + lr) * 32 + lg * 8];
    __builtin_amdgcn_s_setprio(1);
#pragma unroll
    for (int mi = 0; mi < 4; mi++)
#pragma unroll
      for (int ni = 0; ni < 4; ni++)
        acc[mi][ni] = __builtin_amdgcn_mfma_f32_16x16x32_bf16(af[mi], bv[ni], acc[mi][ni], 0, 0, 0);
    __builtin_amdgcn_s_setprio(0);

    asm volatile("s_waitcnt lgkmcnt(0)" ::: "memory");
    __builtin_amdgcn_s_barrier();
    cur ^= 1;
  }

#pragma unroll
  for (int mi = 0; mi < 4; mi++)
#pragma unroll
    for (int ni = 0; ni < 4; ni++) {
      const int rowb = m0 + wm + mi * 16 + lg * 4;
      const int colb = n0 + wn + ni * 16 + lr;
      const float bv_ = bias[colb];
      if (EPI == 0) {
        int s = colb >> 10, hh = (colb & 1023) >> 6, d = colb & 63;
        int b = rowb >> 11, t = rowb & 2047;
        if (s == 2) {
          ushort4 o4;
          o4.x = f2bf(acc[mi][ni][0] + bv_);
          o4.y = f2bf(acc[mi][ni][1] + bv_);
          o4.z = f2bf(acc[mi][ni][2] + bv_);
          o4.w = f2bf(acc[mi][ni][3] + bv_);
          *(ushort4*)&vp[((size_t)(b * NHEAD + hh) * HDIM + d) * SEQ + t] = o4;
        } else {
          unsigned short* dst_ = (s == 0) ? qp : kp;
          const float scl = (s == 0) ? 0.18033688f : 1.0f;   // 1/sqrt(D)*log2e
#pragma unroll
          for (int r = 0; r < 4; r++)
            dst_[((size_t)(b * NHEAD + hh) * SEQ + t + r) * HDIM + d] =
                f2bf((acc[mi][ni][r] + bv_) * scl);
        }
      } else {
#pragma unroll
        for (int r = 0; r < 4; r++)
          outp[(size_t)(rowb + r) * N + colb] = acc[mi][ni][r] + bv_;
      }
    }
}

// --------- softmax for one 16q x 64k fragment (swapped S^T layout) ---------
__device__ __forceinline__ void softmax_frag(
    f32x4 (&s)[4], float& m, f32x4& su, f32x4 (&o)[4],
    unsigned short* psrow, int qrow, int kbase, bool needmask,
    int lg, int lr, int pswz)
{
  const float NEG = -1e30f;
  if (needmask) {
#pragma unroll
    for (int n = 0; n < 4; n++)
#pragma unroll
      for (int r = 0; r < 4; r++) {
        if (kbase + n * 16 + lg * 4 + r > qrow) s[n][r] = NEG;
      }
  }
  // tree max (v_max3-friendly)
  float t0 = fmaxf(fmaxf(s[0][0], s[0][1]), fmaxf(s[0][2], s[0][3]));
  float t1 = fmaxf(fmaxf(s[1][0], s[1][1]), fmaxf(s[1][2], s[1][3]));
  float t2 = fmaxf(fmaxf(s[2][0], s[2][1]), fmaxf(s[2][2], s[2][3]));
  float t3 = fmaxf(fmaxf(s[3][0], s[3][1]), fmaxf(s[3][2], s[3][3]));
  float pm = fmaxf(fmaxf(t0, t1), fmaxf(t2, t3));
  // defer-max (T13): common path skips the cross-lane reduce entirely
  if (__any(pm > m + 8.f)) {
    pm = fmaxf(pm, __shfl_xor(pm, 16, 64));
    pm = fmaxf(pm, __shfl_xor(pm, 32, 64));
    float mn = fmaxf(m, pm);
    float fac = exp2_hw(m - mn);
    m = mn;
    float fr[4];
#pragma unroll
    for (int r = 0; r < 4; r++) fr[r] = __shfl(fac, lg * 4 + r, 64);
#pragma unroll
    for (int r = 0; r < 4; r++) su[r] *= fr[r];
#pragma unroll
    for (int n = 0; n < 4; n++)
#pragma unroll
      for (int r = 0; r < 4; r++) o[n][r] *= fr[r];
  }
#pragma unroll
  for (int n = 0; n < 4; n++) {
    float p0 = exp2_hw(s[n][0] - m);
    float p1 = exp2_hw(s[n][1] - m);
    float p2 = exp2_hw(s[n][2] - m);
    float p3 = exp2_hw(s[n][3] - m);
    uint2 pk;
    pk.x = cvtpk_bf16(p0, p1);
    pk.y = cvtpk_bf16(p2, p3);
    int E = (lr * 64 + n * 16 + lg * 4) ^ pswz;
    *(uint2*)&psrow[E] = pk;
  }
}

// ------- causal flash attention, QBLK=128, 8 waves x 1 q-frag each ---------
// R21-proven best: grid (8,64), 512 threads, 16 waves/CU.
__global__ __launch_bounds__(512) void attn_k(
    const unsigned short* __restrict__ Q,
    const unsigned short* __restrict__ K,
    const unsigned short* __restrict__ Vt,
    unsigned short* __restrict__ Y)
{
  __shared__ unsigned short Ks[2][64 * 64];
  __shared__ unsigned short Vs[2][64 * 64];
  __shared__ unsigned short Ps[8][16 * 64];

  const int tid = threadIdx.x;          // 0..511
  const int w = tid >> 6, lane = tid & 63;
  const int lr = lane & 15, lg = lane >> 4;
  const int bh = blockIdx.y;
  const int b = bh >> 4, h = bh & 15;
  const size_t base = (size_t)bh * SEQ * HDIM;
  const float NEG = -1e30f;
  const int pswz = (lr & 7) << 3;

  bf16x8 ones;
#pragma unroll
  for (int e = 0; e < 8; e++) ones[e] = (short)0x3F80;  // bf16 1.0

  // staging geometry (linear LDS dest, pre-swizzled global source)
  const int r0_ = tid >> 3, c0_ = ((tid & 7) ^ (r0_ & 7)) * 8;

  for (int seg = 0; seg < 2; seg++) {
    const int qb = seg ? (int)blockIdx.x : (15 - (int)blockIdx.x);
    const int qw0 = qb * 128 + w * 16;   // this wave's 16 q-rows
    const int nk = 2 * qb + 2;

    bf16x8 aq[2];
#pragma unroll
    for (int kk = 0; kk < 2; kk++)
      aq[kk] = *(const bf16x8*)
          &Q[base + (size_t)(qw0 + lr) * HDIM + kk * 32 + lg * 8];

    f32x4 o[4] = {};
    f32x4 su = {};
    float m = NEG;

    // stage tile 0 into buf 0
    gload_lds16(K  + base + (size_t)r0_ * HDIM + c0_, &Ks[0][tid * 8]);
    gload_lds16(Vt + base + (size_t)r0_ * SEQ  + c0_, &Vs[0][tid * 8]);
    __syncthreads();

    int cur = 0;
    for (int kb = 0; kb < nk; kb++) {
      if (kb + 1 < nk) {
        gload_lds16(K  + base + (size_t)((kb + 1) * 64 + r0_) * HDIM + c0_,
                    &Ks[cur ^ 1][tid * 8]);
        gload_lds16(Vt + base + (size_t)r0_ * SEQ + (kb + 1) * 64 + c0_,
                    &Vs[cur ^ 1][tid * 8]);
      }

      // fully-masked (wave,tile) pairs skip compute (barrier still hit)
      const bool active = (kb * 64 <= qw0 + 15);
      if (active) {
        // ---- S^T = K Q^T ----
        f32x4 s[4] = {};
        __builtin_amdgcn_s_setprio(1);
#pragma unroll
        for (int kk = 0; kk < 2; kk++) {
          bf16x8 bk[4];
#pragma unroll
          for (int n = 0; n < 4; n++) {
            int E = (n * 16 + lr) * 64 + kk * 32 + lg * 8;
            bk[n] = *(const bf16x8*)&Ks[cur][E ^ pswz];
          }
#pragma unroll
          for (int n = 0; n < 4; n++)
            s[n] = __builtin_amdgcn_mfma_f32_16x16x32_bf16(bk[n], aq[kk], s[n], 0, 0, 0);
        }
        __builtin_amdgcn_s_setprio(0);

        const int kbase = kb * 64;
        softmax_frag(s, m, su, o, &Ps[w][0],
                     qw0 + lr, kbase, kbase + 63 > qw0, lg, lr, pswz);

        // ---- O += P V ; row-sum via ones-column MFMA ----
        __builtin_amdgcn_s_setprio(1);
#pragma unroll
        for (int kc = 0; kc < 2; kc++) {
          bf16x8 ap = *(const bf16x8*)&Ps[w][(lr * 64 + kc * 32 + lg * 8) ^ pswz];
          su = __builtin_amdgcn_mfma_f32_16x16x32_bf16(ap, ones, su, 0, 0, 0);
#pragma unroll
          for (int n = 0; n < 4; n++) {
            int E = (n * 16 + lr) * 64 + kc * 32 + lg * 8;
            bf16x8 bv = *(const bf16x8*)&Vs[cur][E ^ pswz];
            o[n] = __builtin_amdgcn_mfma_f32_16x16x32_bf16(ap, bv, o[n], 0, 0, 0);
          }
        }
        __builtin_amdgcn_s_setprio(0);
      }

      __syncthreads();
      cur ^= 1;
    }

    // ---- per-seg epilogue: normalize (su already in O-layout), write Y ----
    float inv[4];
#pragma unroll
    for (int r = 0; r < 4; r++) inv[r] = 1.f / su[r];
#pragma unroll
    for (int n = 0; n < 4; n++)
#pragma unroll
      for (int r = 0; r < 4; r++) {
        int col = h * HDIM + n * 16 + lr;
        int t0 = qw0 + lg * 4 + r;
        Y[((size_t)(b * SEQ + t0)) * EMBED + col] = f2bf(o[n][r] * inv[r]);
      }
  }
}

// ---------------- host launch ----------------
extern "C" void kernel_launch(void* const* d_in, const int* in_sizes, int n_in,
                              void* d_out, int out_size, void* d_ws, size_t ws_size,
                              hipStream_t stream) {
  const float* x     = (const float*)d_in[0];
  const float* w_qkv = (const float*)d_in[1];
  const float* b_qkv = (const float*)d_in[2];
  const float* w_out = (const float*)d_in[3];
  const float* b_out = (const float*)d_in[4];
  float* outp = (float*)d_out;

  char* ws = (char*)d_ws;
  unsigned short* xb    = (unsigned short*)ws; ws += (size_t)BT * EMBED * 2;
  unsigned short* wqkvT = (unsigned short*)ws; ws += (size_t)NQKV * EMBED * 2;
  unsigned short* woutT = (unsigned short*)ws; ws += (size_t)EMBED * EMBED * 2;
  unsigned short* Qb    = (unsigned short*)ws; ws += (size_t)BATCH * NHEAD * SEQ * HDIM * 2;
  unsigned short* Kb    = (unsigned short*)ws; ws += (size_t)BATCH * NHEAD * SEQ * HDIM * 2;
  unsigned short* Vb    = (unsigned short*)ws; ws += (size_t)BATCH * NHEAD * SEQ * HDIM * 2;
  unsigned short* Yb    = (unsigned short*)ws; ws += (size_t)BT * EMBED * 2;

  cvt_f32_bf16_k<<<(BT * EMBED) / 1024, 256, 0, stream>>>(x, xb, BT * EMBED);
  transpose_cvt_k<<<dim3(NQKV / 32, EMBED / 32), dim3(32, 8), 0, stream>>>(w_qkv, wqkvT, EMBED, NQKV);
  transpose_cvt_k<<<dim3(EMBED / 32, EMBED / 32), dim3(32, 8), 0, stream>>>(w_out, woutT, EMBED, EMBED);

  gemm_bt<0><<<dim3(BT / 128, NQKV / 128), 256, 0, stream>>>(
      xb, wqkvT, b_qkv, Qb, Kb, Vb, nullptr, BT, NQKV, EMBED);

  attn_k<<<dim3(8, BATCH * NHEAD), 512, 0, stream>>>(Qb, Kb, Vb, Yb);

  gemm_bt<1><<<dim3(BT / 128, EMBED / 128), 256, 0, stream>>>(
      Yb, woutT, b_out, nullptr, nullptr, nullptr, outp, BT, EMBED, EMBED);
}